// Round 6
// baseline (103.281 us; speedup 1.0000x reference)
//
#include <hip/hip_runtime.h>
#include <hip/hip_bf16.h>
#include <stdint.h>

#define NROW 4096
#define DIM  512
#define BM   128
#define BN   128
#define BK   64
#define NKT  (DIM / BK)   // 8 k-tiles

typedef __attribute__((ext_vector_type(8)))  short short8;    // 8 bf16 = 4 VGPRs
typedef __attribute__((ext_vector_type(16))) float floatx16;  // MFMA 32x32 C/D

typedef const __attribute__((address_space(1))) void gvoid_t;
typedef __attribute__((address_space(3))) void       svoid_t;

__device__ __forceinline__ unsigned short f32_to_bf16_rne(float f) {
    unsigned u = __float_as_uint(f);
    u += 0x7FFFu + ((u >> 16) & 1u);
    return (unsigned short)(u >> 16);
}

// Pre-swizzled tile-major layout (R5, verified): slab (G=row/8, kt) of 512
// shorts holds [l3=row%8][p] = 16-B chunk of row 8G+l3 at k-chunk kt*8+(p^l3).
// Staging then reads fully contiguous 1 KB per wave-instruction.
// Also packs per-row metadata meta[row] = {sq, bits(y*4+ds)} for the epilogue.
__global__ __launch_bounds__(256) void prep_kernel(
    const float* __restrict__ X, const int* __restrict__ ds,
    const int* __restrict__ y, unsigned short* __restrict__ Xpre,
    float2* __restrict__ meta, float* __restrict__ out)
{
    const int wave = threadIdx.x >> 6;
    const int lane = threadIdx.x & 63;
    const int row  = blockIdx.x * 4 + wave;
    const float4* xr = (const float4*)(X + (size_t)row * DIM);
    float4 v0 = xr[2 * lane];
    float4 v1 = xr[2 * lane + 1];
    float s = v0.x*v0.x + v0.y*v0.y + v0.z*v0.z + v0.w*v0.w
            + v1.x*v1.x + v1.y*v1.y + v1.z*v1.z + v1.w*v1.w;
    uint4 pk;
    pk.x = f32_to_bf16_rne(v0.x) | ((unsigned)f32_to_bf16_rne(v0.y) << 16);
    pk.y = f32_to_bf16_rne(v0.z) | ((unsigned)f32_to_bf16_rne(v0.w) << 16);
    pk.z = f32_to_bf16_rne(v1.x) | ((unsigned)f32_to_bf16_rne(v1.y) << 16);
    pk.w = f32_to_bf16_rne(v1.z) | ((unsigned)f32_to_bf16_rne(v1.w) << 16);
    const int G   = row >> 3;
    const int l3r = row & 7;
    const int kt  = lane >> 3;
    const int p   = (lane & 7) ^ l3r;
    *(uint4*)(Xpre + (size_t)G * 4096 + kt * 512 + l3r * 64 + p * 8) = pk;
    #pragma unroll
    for (int off = 32; off; off >>= 1) s += __shfl_xor(s, off);
    if (lane == 0)
        meta[row] = make_float2(s, __int_as_float(y[row] * 4 + ds[row]));
    if (blockIdx.x == 0 && threadIdx.x < 2) out[threadIdx.x] = 0.0f;
}

// Triangular 128x128 Gram tiles, 512 threads (8 waves, 2x4, 64x32 each via
// two 32x32x16 MFMAs), LDS dbuf + single barrier per kt, 1-KB staging loads.
__global__ __launch_bounds__(512, 4) void ccsa_kernel(
    const unsigned short* __restrict__ Xpre, const float2* __restrict__ meta,
    const int* __restrict__ ncls, const int* __restrict__ ndom,
    float* __restrict__ out)
{
    __shared__ __align__(16) unsigned short As[2 * BM * BK];  // 32 KB
    __shared__ __align__(16) unsigned short Bs[2 * BN * BK];  // 32 KB
    __shared__ float red[16];

    // triangular decode: block t -> (bi_t <= bj_t), 528 blocks
    const int t = blockIdx.x;
    int r = (int)((sqrtf(8.0f * (float)t + 1.0f) - 1.0f) * 0.5f);
    while ((r + 1) * (r + 2) / 2 <= t) ++r;
    while (r * (r + 1) / 2 > t) --r;
    const int bj_t = r;
    const int bi_t = t - r * (r + 1) / 2;
    const bool diag = (bi_t == bj_t);
    const int bm0 = bi_t * BM;
    const int bn0 = bj_t * BN;
    const int GA = bm0 >> 3;
    const int GB = bn0 >> 3;

    const int tid    = threadIdx.x;
    const int wave   = tid >> 6;
    const int lane   = tid & 63;
    const int warp_m = wave >> 2;       // 0..1 : 64-row band
    const int warp_n = wave & 3;        // 0..3 : 32-col band
    const int l31    = lane & 31;
    const int l7     = lane & 7;
    const int h      = lane >> 5;       // k-half within a 16-k MFMA step

    // j-side metadata: col = lane&31 (one j per lane per wave), loop-invariant
    const int jcol = bn0 + warp_n * 32 + l31;
    const float2 mj = meta[jcol];
    const float sqj = mj.x;
    const int   ydj = __float_as_int(mj.y);
    const int   dj  = ydj & 3, yj = ydj >> 2;

    floatx16 acc[2];
    #pragma unroll
    for (int a = 0; a < 2; ++a)
        #pragma unroll
        for (int e = 0; e < 16; ++e) acc[a][e] = 0.f;

    // diagonal tiles: A-tile == B-tile; stage once, read B-frags from As.
    const unsigned short* Bbase = diag ? As : Bs;

    #define STAGE(buf, kt)                                                    \
        do {                                                                  \
            _Pragma("unroll")                                                 \
            for (int is = 0; is < 2; ++is) {                                  \
                const int c = is * 8 + wave;                                  \
                __builtin_amdgcn_global_load_lds(                             \
                    (gvoid_t*)(Xpre + (size_t)(GA + c) * 4096 + (kt) * 512    \
                               + lane * 8),                                   \
                    (svoid_t*)(&As[(buf) * 8192 + c * 512 + lane * 8]),       \
                    16, 0, 0);                                                \
                if (!diag)                                                    \
                    __builtin_amdgcn_global_load_lds(                         \
                        (gvoid_t*)(Xpre + (size_t)(GB + c) * 4096 + (kt) * 512\
                                   + lane * 8),                               \
                        (svoid_t*)(&Bs[(buf) * 8192 + c * 512 + lane * 8]),   \
                        16, 0, 0);                                            \
            }                                                                 \
        } while (0)

    const int rowA0 = (warp_m * 64 + l31) * 64;        // LDS row offsets
    const int rowA1 = (warp_m * 64 + 32 + l31) * 64;
    const int rowB  = (warp_n * 32 + l31) * 64;

    STAGE(0, 0);
    for (int kt = 0; kt < NKT; ++kt) {
        const int cur = kt & 1;
        __syncthreads();                      // drains prev-phase loads
        if (kt + 1 < NKT) STAGE(cur ^ 1, kt + 1);

        #pragma unroll
        for (int s = 0; s < 4; ++s) {         // four 16-k steps per kt
            const int phys = ((2 * s + h) ^ l7) * 8;   // un-swizzle
            const short8 av0 = *(const short8*)(&As[cur * 8192 + rowA0 + phys]);
            const short8 av1 = *(const short8*)(&As[cur * 8192 + rowA1 + phys]);
            const short8 bv  = *(const short8*)(&Bbase[cur * 8192 + rowB + phys]);
            acc[0] = __builtin_amdgcn_mfma_f32_32x32x16_bf16(av0, bv, acc[0], 0, 0, 0);
            acc[1] = __builtin_amdgcn_mfma_f32_32x32x16_bf16(av1, bv, acc[1], 0, 0, 0);
        }
    }
    #undef STAGE

    // Epilogue: 32x32 C/D map col=lane&31, row=(reg&3)+8*(reg>>2)+4*(lane>>5)
    // (m74/m101 verified; transpose-errors invisible here by Gram symmetry).
    float sa = 0.f, ss = 0.f;
    #pragma unroll
    for (int tm = 0; tm < 2; ++tm) {
        float2 mi[16];
        #pragma unroll
        for (int reg = 0; reg < 16; ++reg) {
            const int i = bm0 + warp_m * 64 + tm * 32
                        + (reg & 3) + 8 * (reg >> 2) + 4 * h;
            mi[reg] = meta[i];
        }
        if (diag) {
            #pragma unroll
            for (int reg = 0; reg < 16; ++reg) {
                const int ydi = __float_as_int(mi[reg].y);
                const int di = ydi & 3, yi = ydi >> 2;
                if (di < dj) {
                    const float d2   = mi[reg].x + sqj - 2.0f * acc[tm][reg];
                    const float dist = sqrtf(fmaxf(d2, 0.f));
                    if (yi == yj)     sa += dist;
                    else if (yi < yj) ss += fmaxf(0.f, 1.f - dist);
                }
            }
        } else {
            #pragma unroll
            for (int reg = 0; reg < 16; ++reg) {
                const int ydi = __float_as_int(mi[reg].y);
                const int di = ydi & 3, yi = ydi >> 2;
                if (di != dj) {
                    const float d2   = mi[reg].x + sqj - 2.0f * acc[tm][reg];
                    const float dist = sqrtf(fmaxf(d2, 0.f));
                    if (yi == yj) {
                        sa += dist;
                    } else {
                        const bool take = (di < dj) ? (yi < yj) : (yj < yi);
                        if (take) ss += fmaxf(0.f, 1.f - dist);
                    }
                }
            }
        }
    }
    #pragma unroll
    for (int off = 32; off; off >>= 1) {
        sa += __shfl_xor(sa, off);
        ss += __shfl_xor(ss, off);
    }
    if (lane == 0) { red[wave] = sa; red[8 + wave] = ss; }
    __syncthreads();
    if (tid == 0) {
        float tsa = 0.f, tss = 0.f;
        #pragma unroll
        for (int w = 0; w < 8; ++w) { tsa += red[w]; tss += red[8 + w]; }
        const int nc = *ncls, nd = *ndom;
        const float n_sa = (float)(nc * (nd * (nd - 1) / 2));
        const float n_s  = (float)((nc * (nc - 1) / 2) * (nd * (nd - 1) / 2));
        atomicAdd(out + 0, tsa * 0.5f / n_sa);
        atomicAdd(out + 1, tss * 0.5f / n_s);
    }
}

extern "C" void kernel_launch(void* const* d_in, const int* in_sizes, int n_in,
                              void* d_out, int out_size, void* d_ws, size_t ws_size,
                              hipStream_t stream) {
    (void)in_sizes; (void)n_in; (void)out_size; (void)ws_size;
    const float* X  = (const float*)d_in[0];
    const int*   ds = (const int*)d_in[1];
    const int*   y  = (const int*)d_in[2];
    const int*   nc = (const int*)d_in[3];
    const int*   nd = (const int*)d_in[4];
    float* out = (float*)d_out;

    unsigned short* Xpre = (unsigned short*)d_ws;                       // 4 MB
    float2* meta = (float2*)((char*)d_ws + (size_t)NROW * DIM * 2);     // 32 KB

    prep_kernel<<<NROW / 4, 256, 0, stream>>>(X, ds, y, Xpre, meta, out);
    const int ntiles = NROW / BM;                                       // 32
    const int nblocks = ntiles * (ntiles + 1) / 2;                      // 528
    ccsa_kernel<<<nblocks, 512, 0, stream>>>(Xpre, meta, nc, nd, out);
}

// Round 7
// 100.415 us; speedup vs baseline: 1.0285x; 1.0285x over previous
//
#include <hip/hip_runtime.h>
#include <hip/hip_bf16.h>
#include <stdint.h>

#define NROW 4096
#define DIM  512
#define BM   128
#define BN   128
#define BK   32
#define NKT  (DIM / BK)   // 16 k-tiles of 32

typedef __attribute__((ext_vector_type(8))) short  short8;   // 8 bf16 = 4 VGPRs
typedef __attribute__((ext_vector_type(4))) float  floatx4;  // MFMA 16x16 C/D

typedef const __attribute__((address_space(1))) void gvoid_t;
typedef __attribute__((address_space(3))) void       svoid_t;

__device__ __forceinline__ unsigned short f32_to_bf16_rne(float f) {
    unsigned u = __float_as_uint(f);
    u += 0x7FFFu + ((u >> 16) & 1u);
    return (unsigned short)(u >> 16);
}

// kt-major pre-swizzled layout: slab (kt=k/32, G=row/8) of 256 shorts holds
// [l3=row%8][p] = 16-B chunk, p = chunk ^ (row&3), chunk = (k%32)/8.
// A 128-row panel's kt-slab is then 16 consecutive slabs = 8 KB contiguous:
// staging is base + tid*16B, one global_load_lds per thread per panel per kt.
// meta[row] = {sq_fp32, bits(y*4+ds)} for the epilogue.
__global__ __launch_bounds__(256) void prep_kernel(
    const float* __restrict__ X, const int* __restrict__ ds,
    const int* __restrict__ y, unsigned short* __restrict__ Xpre,
    float2* __restrict__ meta, float* __restrict__ out)
{
    const int wave = threadIdx.x >> 6;
    const int lane = threadIdx.x & 63;
    const int row  = blockIdx.x * 4 + wave;
    const float4* xr = (const float4*)(X + (size_t)row * DIM);
    float4 v0 = xr[2 * lane];
    float4 v1 = xr[2 * lane + 1];
    float s = v0.x*v0.x + v0.y*v0.y + v0.z*v0.z + v0.w*v0.w
            + v1.x*v1.x + v1.y*v1.y + v1.z*v1.z + v1.w*v1.w;
    uint4 pk;
    pk.x = f32_to_bf16_rne(v0.x) | ((unsigned)f32_to_bf16_rne(v0.y) << 16);
    pk.y = f32_to_bf16_rne(v0.z) | ((unsigned)f32_to_bf16_rne(v0.w) << 16);
    pk.z = f32_to_bf16_rne(v1.x) | ((unsigned)f32_to_bf16_rne(v1.y) << 16);
    pk.w = f32_to_bf16_rne(v1.z) | ((unsigned)f32_to_bf16_rne(v1.w) << 16);
    const int G     = row >> 3;
    const int l3r   = row & 7;
    const int kt32  = lane >> 2;          // lane covers k = lane*8..lane*8+7
    const int chunk = lane & 3;
    const int p     = chunk ^ (row & 3);
    *(uint4*)(Xpre + ((size_t)kt32 * 512 + G) * 256 + l3r * 32 + p * 8) = pk;
    #pragma unroll
    for (int off = 32; off; off >>= 1) s += __shfl_xor(s, off);
    if (lane == 0)
        meta[row] = make_float2(s, __int_as_float(y[row] * 4 + ds[row]));
    if (blockIdx.x == 0 && threadIdx.x < 2) out[threadIdx.x] = 0.0f;
}

// Triangular 128x128 Gram tiles, 512 threads (8 waves, 2x4 grid, 64x32 each
// via 4x2 16x16x32 MFMAs), BK=32 LDS double-buffer (32 KB total) + single
// barrier per kt.  3 blocks/CU co-resident (launch_bounds 512,6) -> all 528
// blocks resident at once: no sequential tail round (R5's ~1/3 loss).
__global__ __launch_bounds__(512, 6) void ccsa_kernel(
    const unsigned short* __restrict__ Xpre, const float2* __restrict__ meta,
    const int* __restrict__ ncls, const int* __restrict__ ndom,
    float* __restrict__ out)
{
    __shared__ __align__(16) unsigned short As[2 * BM * BK];  // 16 KB
    __shared__ __align__(16) unsigned short Bs[2 * BN * BK];  // 16 KB
    __shared__ float red[16];

    // triangular decode: block t -> (bi_t <= bj_t), 528 blocks
    const int t = blockIdx.x;
    int r = (int)((sqrtf(8.0f * (float)t + 1.0f) - 1.0f) * 0.5f);
    while ((r + 1) * (r + 2) / 2 <= t) ++r;
    while (r * (r + 1) / 2 > t) --r;
    const int bj_t = r;
    const int bi_t = t - r * (r + 1) / 2;
    const bool diag = (bi_t == bj_t);
    const int bm0 = bi_t * BM;
    const int bn0 = bj_t * BN;
    const int GA = bm0 >> 3;
    const int GB = bn0 >> 3;

    const int tid    = threadIdx.x;
    const int wave   = tid >> 6;
    const int lane   = tid & 63;
    const int warp_m = wave >> 2;       // 0..1 : 64-row band
    const int warp_n = wave & 3;        // 0..3 : 32-col band
    const int m15    = lane & 15;
    const int quad   = lane >> 4;
    const int sw     = m15 & 3;         // row&3 for un-swizzle

    // j-side metadata, loop-invariant
    float sqj[2]; int yj[2], dj[2];
    #pragma unroll
    for (int tn = 0; tn < 2; ++tn) {
        const float2 mj = meta[bn0 + warp_n * 32 + tn * 16 + m15];
        sqj[tn] = mj.x;
        const int ydj = __float_as_int(mj.y);
        dj[tn] = ydj & 3; yj[tn] = ydj >> 2;
    }

    floatx4 acc[4][2];
    #pragma unroll
    for (int a = 0; a < 4; ++a)
        #pragma unroll
        for (int b = 0; b < 2; ++b)
            acc[a][b] = (floatx4){0.f, 0.f, 0.f, 0.f};

    // diagonal tiles: A-tile == B-tile; stage once, read B from As.
    const unsigned short* Bbase = diag ? As : Bs;

    // staging: one 16-B load per thread per panel per kt; src fully linear.
    #define STAGE(buf, kt)                                                    \
        do {                                                                  \
            __builtin_amdgcn_global_load_lds(                                 \
                (gvoid_t*)(Xpre + ((size_t)(kt) * 512 + GA) * 256 + tid * 8), \
                (svoid_t*)(&As[(buf) * 4096 + tid * 8]), 16, 0, 0);           \
            if (!diag)                                                        \
                __builtin_amdgcn_global_load_lds(                             \
                    (gvoid_t*)(Xpre + ((size_t)(kt) * 512 + GB) * 256         \
                               + tid * 8),                                    \
                    (svoid_t*)(&Bs[(buf) * 4096 + tid * 8]), 16, 0, 0);       \
        } while (0)

    const int physA = (quad ^ sw) * 8;   // un-swizzled chunk offset (shorts)

    STAGE(0, 0);
    for (int kt = 0; kt < NKT; ++kt) {
        const int cur = kt & 1;
        __syncthreads();                      // drains prev-phase loads
        if (kt + 1 < NKT) STAGE(cur ^ 1, kt + 1);

        short8 a[4], b[2];
        #pragma unroll
        for (int tt = 0; tt < 4; ++tt) {
            const int rla = warp_m * 64 + tt * 16 + m15;
            a[tt] = *(const short8*)(&As[cur * 4096 + rla * 32 + physA]);
        }
        #pragma unroll
        for (int tt = 0; tt < 2; ++tt) {
            const int rlb = warp_n * 32 + tt * 16 + m15;
            b[tt] = *(const short8*)(&Bbase[cur * 4096 + rlb * 32 + physA]);
        }
        #pragma unroll
        for (int tm = 0; tm < 4; ++tm)
            #pragma unroll
            for (int tn = 0; tn < 2; ++tn)
                acc[tm][tn] = __builtin_amdgcn_mfma_f32_16x16x32_bf16(
                    a[tm], b[tn], acc[tm][tn], 0, 0, 0);
    }
    #undef STAGE

    // Epilogue: C/D map col=lane&15, row=quad*4+reg (m89/m91 verified)
    float sa = 0.f, ss = 0.f;
    #pragma unroll
    for (int tm = 0; tm < 4; ++tm) {
        #pragma unroll
        for (int rr = 0; rr < 4; ++rr) {
            const int i = bm0 + warp_m * 64 + tm * 16 + quad * 4 + rr;
            const float2 mi = meta[i];
            const int ydi = __float_as_int(mi.y);
            const int di = ydi & 3, yi = ydi >> 2;
            #pragma unroll
            for (int tn = 0; tn < 2; ++tn) {
                if (diag) {
                    if (di < dj[tn]) {
                        const float d2   = mi.x + sqj[tn] - 2.0f * acc[tm][tn][rr];
                        const float dist = sqrtf(fmaxf(d2, 0.f));
                        if (yi == yj[tn])     sa += dist;
                        else if (yi < yj[tn]) ss += fmaxf(0.f, 1.f - dist);
                    }
                } else {
                    // fold both orientations (dist symmetric; exactly one
                    // orientation has d_lt when ds differ)
                    if (di != dj[tn]) {
                        const float d2   = mi.x + sqj[tn] - 2.0f * acc[tm][tn][rr];
                        const float dist = sqrtf(fmaxf(d2, 0.f));
                        if (yi == yj[tn]) {
                            sa += dist;
                        } else {
                            const bool take = (di < dj[tn]) ? (yi < yj[tn])
                                                            : (yj[tn] < yi);
                            if (take) ss += fmaxf(0.f, 1.f - dist);
                        }
                    }
                }
            }
        }
    }
    #pragma unroll
    for (int off = 32; off; off >>= 1) {
        sa += __shfl_xor(sa, off);
        ss += __shfl_xor(ss, off);
    }
    if (lane == 0) { red[wave] = sa; red[8 + wave] = ss; }
    __syncthreads();
    if (tid == 0) {
        float tsa = 0.f, tss = 0.f;
        #pragma unroll
        for (int w = 0; w < 8; ++w) { tsa += red[w]; tss += red[8 + w]; }
        const int nc = *ncls, nd = *ndom;
        const float n_sa = (float)(nc * (nd * (nd - 1) / 2));
        const float n_s  = (float)((nc * (nc - 1) / 2) * (nd * (nd - 1) / 2));
        atomicAdd(out + 0, tsa * 0.5f / n_sa);
        atomicAdd(out + 1, tss * 0.5f / n_s);
    }
}

extern "C" void kernel_launch(void* const* d_in, const int* in_sizes, int n_in,
                              void* d_out, int out_size, void* d_ws, size_t ws_size,
                              hipStream_t stream) {
    (void)in_sizes; (void)n_in; (void)out_size; (void)ws_size;
    const float* X  = (const float*)d_in[0];
    const int*   ds = (const int*)d_in[1];
    const int*   y  = (const int*)d_in[2];
    const int*   nc = (const int*)d_in[3];
    const int*   nd = (const int*)d_in[4];
    float* out = (float*)d_out;

    unsigned short* Xpre = (unsigned short*)d_ws;                       // 4 MB
    float2* meta = (float2*)((char*)d_ws + (size_t)NROW * DIM * 2);     // 32 KB

    prep_kernel<<<NROW / 4, 256, 0, stream>>>(X, ds, y, Xpre, meta, out);
    const int ntiles = NROW / BM;                                       // 32
    const int nblocks = ntiles * (ntiles + 1) / 2;                      // 528
    ccsa_kernel<<<nblocks, 512, 0, stream>>>(Xpre, meta, nc, nd, out);
}